// Round 10
// baseline (123.066 us; speedup 1.0000x reference)
//
#include <hip/hip_runtime.h>

#define NTOK 49
#define NH 4
#define HD 32
#define CIN 384
#define NW 64
#define NPAD 64
#define NPER 8
#define SCALE_F 0.1767766952966369f

typedef _Float16 f16x8 __attribute__((ext_vector_type(8)));
typedef float f32x16 __attribute__((ext_vector_type(16)));
typedef __fp16 fp16x2 __attribute__((ext_vector_type(2)));

__device__ __forceinline__ unsigned int pkh(float a, float b) {
    fp16x2 h = __builtin_amdgcn_cvt_pkrtz(a, b);
    return __builtin_bit_cast(unsigned int, h);
}

// cmT[w*4+h][j][i] = mask[h][i][j] + rot[w][i][j], padded to 64x64,
// j>=49 -> -1e30 (kills padded keys in softmax), i>=49 -> 0.
__global__ __launch_bounds__(64) void prep_cmask(
    const float* __restrict__ mask,
    const float* __restrict__ rot,
    float* __restrict__ cmT)
{
    const int wh = blockIdx.x;          // w*4 + h
    const int w = wh >> 2, h = wh & 3;
    const int i = threadIdx.x;          // 0..63
    for (int j = 0; j < NPAD; ++j) {
        float v;
        if (j >= NTOK) v = -1e30f;
        else if (i >= NTOK) v = 0.f;
        else v = mask[(h * NTOK + i) * NTOK + j] + rot[(w * NTOK + i) * NTOK + j];
        cmT[((size_t)wh * NPAD + j) * NPAD + i] = v;
    }
}

// Persistent 2-wave blocks: each block loops over NPER consecutive (b,h)
// problems with double-buffered LDS. Per-problem math identical to the proven
// R9 kernel: wave it owns query-half it; S^T = K*Q^T via mfma_32x32x16_f16
// (C: col=i=lane&31, row=j=(r&3)+8*(r>>2)+4*hl+32*jt); softmax lane-local +
// shfl_xor(32); P packed via cvt_pkrtz + one lane^32 exchange.
template<bool USE_CM>
__global__ __launch_bounds__(128) void win_attn_mfma(
    const float* __restrict__ qkv,
    const float* __restrict__ mask,
    const float* __restrict__ rot,
    const float* __restrict__ cmT,
    float* __restrict__ out,
    int nprob)
{
    const int tid = threadIdx.x;
    const int it = tid >> 6;            // wave id = query-half
    const int lane = tid & 63;
    const int l31 = lane & 31;
    const int hl = lane >> 5;

    __shared__ _Float16 Qs[2][NPAD * HD];   // rows >= 49 zeroed
    __shared__ _Float16 Ks[2][NPAD * HD];

    const int p0 = blockIdx.x * NPER;

    // ---- stage problem p into LDS buffer s (both waves cooperate) ----
    auto stage = [&](int p, int s) {
        const int hh = p & 3;
        const int bb = p >> 2;
        const float* base = qkv + (size_t)bb * (NTOK * CIN) + hh * HD;
        #pragma unroll
        for (int t4 = 0; t4 < 4; ++t4) {
            const int idx = tid + t4 * 128;    // 0..511
            const int n = idx >> 3;            // row 0..63
            const int c = idx & 7;             // float4 chunk
            float4 fq = make_float4(0.f, 0.f, 0.f, 0.f);
            float4 fk = fq;
            if (n < NTOK) {
                const float* pp = base + n * CIN + c * 4;
                fq = *reinterpret_cast<const float4*>(pp);
                fk = *reinterpret_cast<const float4*>(pp + 128);
            }
            uint2 uq, uk;
            uq.x = pkh(fq.x * SCALE_F, fq.y * SCALE_F);
            uq.y = pkh(fq.z * SCALE_F, fq.w * SCALE_F);
            uk.x = pkh(fk.x, fk.y);
            uk.y = pkh(fk.z, fk.w);
            *reinterpret_cast<uint2*>(&Qs[s][n * HD + c * 4]) = uq;
            *reinterpret_cast<uint2*>(&Ks[s][n * HD + c * 4]) = uk;
        }
    };

    if (p0 >= nprob) return;
    stage(p0, 0);
    __syncthreads();

    int cur = 0;
    #pragma unroll 1
    for (int t = 0; t < NPER; ++t) {
        const int p = p0 + t;
        if (p >= nprob) break;            // uniform per block
        const int h = p & 3;
        const int b = p >> 2;
        const int w = b & (NW - 1);
        const int i = l31 + 32 * it;

        // ---- combined mask values for this wave's query half ----
        float cm[2][16];
        #pragma unroll
        for (int jt = 0; jt < 2; ++jt) {
            #pragma unroll
            for (int r = 0; r < 16; ++r) {
                const int j = (r & 3) + 8 * (r >> 2) + 4 * hl + 32 * jt;
                if (USE_CM) {
                    cm[jt][r] = cmT[((size_t)(w * 4 + h) * NPAD + j) * NPAD + i];
                } else {
                    float v;
                    if (j >= NTOK) v = -1e30f;
                    else if (i >= NTOK) v = 0.f;
                    else v = mask[(h * NTOK + i) * NTOK + j] + rot[(w * NTOK + i) * NTOK + j];
                    cm[jt][r] = v;
                }
            }
        }

        // ---- V B-fragments (issued early; consumed after softmax) ----
        uint4 vb[4];
        {
            const float* vbase = qkv + (size_t)b * (NTOK * CIN) + 256 + h * HD + l31;
            #pragma unroll
            for (int ks = 0; ks < 4; ++ks) {
                unsigned dd[4];
                #pragma unroll
                for (int ep = 0; ep < 4; ++ep) {
                    const int j0 = 16 * ks + 8 * hl + 2 * ep;
                    const float v0 = (j0     < NTOK) ? vbase[(size_t)j0 * CIN]       : 0.f;
                    const float v1 = (j0 + 1 < NTOK) ? vbase[(size_t)(j0 + 1) * CIN] : 0.f;
                    dd[ep] = pkh(v0, v1);
                }
                vb[ks] = make_uint4(dd[0], dd[1], dd[2], dd[3]);
            }
        }

        // ---- fragments from LDS buffer cur: K both tiles, Q own half ----
        f16x8 ka[2][2], qa[2];
        #pragma unroll
        for (int kt = 0; kt < 2; ++kt) {
            #pragma unroll
            for (int ks = 0; ks < 2; ++ks) {
                ka[kt][ks] = *reinterpret_cast<const f16x8*>(&Ks[cur][(l31 + 32 * kt) * HD + ks * 16 + hl * 8]);
            }
        }
        #pragma unroll
        for (int ks = 0; ks < 2; ++ks) {
            qa[ks] = *reinterpret_cast<const f16x8*>(&Qs[cur][(l31 + 32 * it) * HD + ks * 16 + hl * 8]);
        }

        // ---- stage next problem into the other buffer (latency hides under compute) ----
        if (t + 1 < NPER && p + 1 < nprob) stage(p + 1, cur ^ 1);

        // ---- S^T = K * Q^T for this half ----
        f32x16 acc[2];
        #pragma unroll
        for (int jt = 0; jt < 2; ++jt) {
            f32x16 a;
            #pragma unroll
            for (int r = 0; r < 16; ++r) a[r] = 0.f;
            a = __builtin_amdgcn_mfma_f32_32x32x16_f16(ka[jt][0], qa[0], a, 0, 0, 0);
            a = __builtin_amdgcn_mfma_f32_32x32x16_f16(ka[jt][1], qa[1], a, 0, 0, 0);
            acc[jt] = a;
        }

        // ---- + mask, softmax over j (32 lane-local + lane^32 partner) ----
        float m = -3e38f;
        #pragma unroll
        for (int jt = 0; jt < 2; ++jt) {
            #pragma unroll
            for (int r = 0; r < 16; ++r) {
                acc[jt][r] += cm[jt][r];
                m = fmaxf(m, acc[jt][r]);
            }
        }
        m = fmaxf(m, __shfl_xor(m, 32));
        float s = 0.f;
        #pragma unroll
        for (int jt = 0; jt < 2; ++jt) {
            #pragma unroll
            for (int r = 0; r < 16; ++r) {
                const float e = __expf(acc[jt][r] - m);
                acc[jt][r] = e;
                s += e;
            }
        }
        s += __shfl_xor(s, 32);
        const float inv = 1.f / s;
        #pragma unroll
        for (int jt = 0; jt < 2; ++jt) {
            #pragma unroll
            for (int r = 0; r < 16; ++r) acc[jt][r] *= inv;
        }

        // ---- O = P * V ----
        f32x16 oacc;
        #pragma unroll
        for (int r = 0; r < 16; ++r) oacc[r] = 0.f;

        #pragma unroll
        for (int ks = 0; ks < 4; ++ks) {
            const int jt = ks >> 1;
            const int r8 = 8 * (ks & 1);
            const unsigned lo0 = pkh(acc[jt][r8 + 0], acc[jt][r8 + 1]);
            const unsigned lo1 = pkh(acc[jt][r8 + 2], acc[jt][r8 + 3]);
            const unsigned hi0 = pkh(acc[jt][r8 + 4], acc[jt][r8 + 5]);
            const unsigned hi1 = pkh(acc[jt][r8 + 6], acc[jt][r8 + 7]);
            const unsigned x0 = hl ? lo0 : hi0;
            const unsigned x1 = hl ? lo1 : hi1;
            const unsigned y0 = (unsigned)__shfl_xor((int)x0, 32);
            const unsigned y1 = (unsigned)__shfl_xor((int)x1, 32);
            uint4 pu;
            pu.x = hl ? y0 : lo0;
            pu.y = hl ? y1 : lo1;
            pu.z = hl ? hi0 : y0;
            pu.w = hl ? hi1 : y1;
            const f16x8 pa  = __builtin_bit_cast(f16x8, pu);
            const f16x8 vbk = __builtin_bit_cast(f16x8, vb[ks]);
            oacc = __builtin_amdgcn_mfma_f32_32x32x16_f16(pa, vbk, oacc, 0, 0, 0);
        }

        // ---- store this half: O[i][d], d = l31 ----
        float* obase = out + (size_t)b * NTOK * (NH * HD) + h * HD + l31;
        #pragma unroll
        for (int r = 0; r < 16; ++r) {
            const int io = (r & 3) + 8 * (r >> 2) + 4 * hl + 32 * it;
            if (io < NTOK) obase[(size_t)io * (NH * HD)] = oacc[r];
        }

        __syncthreads();
        cur ^= 1;
    }
}

extern "C" void kernel_launch(void* const* d_in, const int* in_sizes, int n_in,
                              void* d_out, int out_size, void* d_ws, size_t ws_size,
                              hipStream_t stream) {
    const float* qkv  = (const float*)d_in[0];
    const float* mask = (const float*)d_in[1];
    const float* rot  = (const float*)d_in[2];
    float* out = (float*)d_out;

    const int Btot = in_sizes[0] / (NTOK * CIN);  // 4096
    const int nprob = Btot * NH;                  // 16384
    dim3 grid((nprob + NPER - 1) / NPER);         // 2048 persistent blocks

    const size_t cm_bytes = (size_t)NW * NH * NPAD * NPAD * sizeof(float);  // 4 MiB
    if (ws_size >= cm_bytes && d_ws != nullptr) {
        float* cmT = (float*)d_ws;
        prep_cmask<<<dim3(NW * NH), 64, 0, stream>>>(mask, rot, cmT);
        win_attn_mfma<true><<<grid, 128, 0, stream>>>(qkv, mask, rot, cmT, out, nprob);
    } else {
        win_attn_mfma<false><<<grid, 128, 0, stream>>>(qkv, mask, rot, nullptr, out, nprob);
    }
}

// Round 11
// 108.186 us; speedup vs baseline: 1.1375x; 1.1375x over previous
//
#include <hip/hip_runtime.h>

#define NTOK 49
#define NH 4
#define HD 32
#define CIN 384
#define NW 64
#define NPAD 64
#define QKP 136   // LDS row stride in f16 (272 B): 16B-aligned, breaks 256B bank alias
#define SCALE_F 0.1767766952966369f

typedef _Float16 f16x8 __attribute__((ext_vector_type(8)));
typedef float f32x16 __attribute__((ext_vector_type(16)));
typedef __fp16 fp16x2 __attribute__((ext_vector_type(2)));

__device__ __forceinline__ unsigned int pkh(float a, float b) {
    fp16x2 h = __builtin_amdgcn_cvt_pkrtz(a, b);
    return __builtin_bit_cast(unsigned int, h);
}

// cmT[w*4+h][j][i] = mask[h][i][j] + rot[w][i][j], padded to 64x64,
// j>=49 -> -1e30 (kills padded keys in softmax), i>=49 -> 0.
__global__ __launch_bounds__(64) void prep_cmask(
    const float* __restrict__ mask,
    const float* __restrict__ rot,
    float* __restrict__ cmT)
{
    const int wh = blockIdx.x;          // w*4 + h
    const int w = wh >> 2, h = wh & 3;
    const int i = threadIdx.x;          // 0..63
    for (int j = 0; j < NPAD; ++j) {
        float v;
        if (j >= NTOK) v = -1e30f;
        else if (i >= NTOK) v = 0.f;
        else v = mask[(h * NTOK + i) * NTOK + j] + rot[(w * NTOK + i) * NTOK + j];
        cmT[((size_t)wh * NPAD + j) * NPAD + i] = v;
    }
}

// 8-wave block per image-window b: wave wid = (head h=wid>>1, query-half it=wid&1).
// Per-wave math identical to the proven R9 kernel. Staging is whole-row
// (cols 0..255 = all heads' Q+K) fully-coalesced float4 loads.
// S^T = K*Q^T via mfma_32x32x16_f16 (C: col=i=lane&31, row=j=(r&3)+8*(r>>2)+4*hl+32*jt);
// softmax lane-local + shfl_xor(32); P packed via cvt_pkrtz + one lane^32 exchange.
template<bool USE_CM>
__global__ __launch_bounds__(512) void win_attn_mfma(
    const float* __restrict__ qkv,
    const float* __restrict__ mask,
    const float* __restrict__ rot,
    const float* __restrict__ cmT,
    float* __restrict__ out)
{
    const int b = blockIdx.x;
    const int w = b & (NW - 1);
    const int tid = threadIdx.x;
    const int wid = tid >> 6;
    const int h = wid >> 1;             // head
    const int it = wid & 1;             // query-half
    const int lane = tid & 63;
    const int l31 = lane & 31;
    const int hl = lane >> 5;

    __shared__ _Float16 Qs[NPAD * QKP];   // [row][head*32+d], rows >= 49 zeroed
    __shared__ _Float16 Ks[NPAD * QKP];

    const float* base = qkv + (size_t)b * (NTOK * CIN);

    // ---- stage all heads' Q (pre-scaled) + K as f16 (coalesced full rows) ----
    // Q+K span = cols 0..255 -> 64 float4 chunks per row, 49 rows = 3136 chunks.
    for (int e = tid; e < NTOK * 64; e += 512) {
        const int n = e >> 6;            // row
        const int c = e & 63;            // float4 chunk within row
        const int col = c * 4;           // 0..252
        const float4 f = *reinterpret_cast<const float4*>(base + n * CIN + col);
        uint2 u;
        if (col < 128) {
            u.x = pkh(f.x * SCALE_F, f.y * SCALE_F);
            u.y = pkh(f.z * SCALE_F, f.w * SCALE_F);
            *reinterpret_cast<uint2*>(&Qs[n * QKP + col]) = u;
        } else {
            u.x = pkh(f.x, f.y);
            u.y = pkh(f.z, f.w);
            *reinterpret_cast<uint2*>(&Ks[n * QKP + (col - 128)]) = u;
        }
    }
    // zero-fill rows 49..63 (both arrays, cols 0..127 each)
    for (int e = tid; e < 15 * 64; e += 512) {
        const int n = NTOK + (e >> 6);
        const int c = e & 63;
        const int col = c * 4;
        const uint2 z = make_uint2(0u, 0u);
        if (col < 128) *reinterpret_cast<uint2*>(&Qs[n * QKP + col]) = z;
        else           *reinterpret_cast<uint2*>(&Ks[n * QKP + (col - 128)]) = z;
    }

    // ---- combined mask values for this wave's (h, it) ----
    const int i = l31 + 32 * it;
    float cm[2][16];
    #pragma unroll
    for (int jt = 0; jt < 2; ++jt) {
        #pragma unroll
        for (int r = 0; r < 16; ++r) {
            const int j = (r & 3) + 8 * (r >> 2) + 4 * hl + 32 * jt;
            if (USE_CM) {
                cm[jt][r] = cmT[((size_t)(w * 4 + h) * NPAD + j) * NPAD + i];
            } else {
                float v;
                if (j >= NTOK) v = -1e30f;
                else if (i >= NTOK) v = 0.f;
                else v = mask[(h * NTOK + i) * NTOK + j] + rot[(w * NTOK + i) * NTOK + j];
                cm[jt][r] = v;
            }
        }
    }

    __syncthreads();

    // ---- fragments from LDS: K both tiles, Q own half; head offset h*32 ----
    f16x8 ka[2][2], qa[2];
    #pragma unroll
    for (int kt = 0; kt < 2; ++kt) {
        #pragma unroll
        for (int ks = 0; ks < 2; ++ks) {
            ka[kt][ks] = *reinterpret_cast<const f16x8*>(&Ks[(l31 + 32 * kt) * QKP + h * HD + ks * 16 + hl * 8]);
        }
    }
    #pragma unroll
    for (int ks = 0; ks < 2; ++ks) {
        qa[ks] = *reinterpret_cast<const f16x8*>(&Qs[(l31 + 32 * it) * QKP + h * HD + ks * 16 + hl * 8]);
    }

    // ---- S^T = K * Q^T for this half ----
    f32x16 acc[2];
    #pragma unroll
    for (int jt = 0; jt < 2; ++jt) {
        f32x16 a;
        #pragma unroll
        for (int r = 0; r < 16; ++r) a[r] = 0.f;
        a = __builtin_amdgcn_mfma_f32_32x32x16_f16(ka[jt][0], qa[0], a, 0, 0, 0);
        a = __builtin_amdgcn_mfma_f32_32x32x16_f16(ka[jt][1], qa[1], a, 0, 0, 0);
        acc[jt] = a;
    }

    // ---- + mask, softmax over j (32 lane-local + lane^32 partner) ----
    float m = -3e38f;
    #pragma unroll
    for (int jt = 0; jt < 2; ++jt) {
        #pragma unroll
        for (int r = 0; r < 16; ++r) {
            acc[jt][r] += cm[jt][r];
            m = fmaxf(m, acc[jt][r]);
        }
    }
    m = fmaxf(m, __shfl_xor(m, 32));
    float s = 0.f;
    #pragma unroll
    for (int jt = 0; jt < 2; ++jt) {
        #pragma unroll
        for (int r = 0; r < 16; ++r) {
            const float e = __expf(acc[jt][r] - m);
            acc[jt][r] = e;
            s += e;
        }
    }
    s += __shfl_xor(s, 32);
    const float inv = 1.f / s;
    #pragma unroll
    for (int jt = 0; jt < 2; ++jt) {
        #pragma unroll
        for (int r = 0; r < 16; ++r) acc[jt][r] *= inv;
    }

    // ---- O = P * V (V fragments from global, as R9) ----
    f32x16 oacc;
    #pragma unroll
    for (int r = 0; r < 16; ++r) oacc[r] = 0.f;

    #pragma unroll
    for (int ks = 0; ks < 4; ++ks) {
        // V B-fragment: lane holds V[16ks+8hl+e][d=l31]
        unsigned int vd[4];
        #pragma unroll
        for (int ep = 0; ep < 4; ++ep) {
            const int j0 = 16 * ks + 8 * hl + 2 * ep;
            float v0 = 0.f, v1 = 0.f;
            if (j0 < NTOK)
                v0 = qkv[((size_t)b * NTOK + j0) * CIN + 256 + h * HD + l31];
            if (j0 + 1 < NTOK)
                v1 = qkv[((size_t)b * NTOK + j0 + 1) * CIN + 256 + h * HD + l31];
            vd[ep] = pkh(v0, v1);
        }
        uint4 vu = make_uint4(vd[0], vd[1], vd[2], vd[3]);
        const f16x8 vb = __builtin_bit_cast(f16x8, vu);

        const int jt = ks >> 1;
        const int r8 = 8 * (ks & 1);
        // pack own j-pairs; exchange the half the partner needs (lane ^ 32)
        const unsigned lo0 = pkh(acc[jt][r8 + 0], acc[jt][r8 + 1]);
        const unsigned lo1 = pkh(acc[jt][r8 + 2], acc[jt][r8 + 3]);
        const unsigned hi0 = pkh(acc[jt][r8 + 4], acc[jt][r8 + 5]);
        const unsigned hi1 = pkh(acc[jt][r8 + 6], acc[jt][r8 + 7]);
        const unsigned x0 = hl ? lo0 : hi0;
        const unsigned x1 = hl ? lo1 : hi1;
        const unsigned y0 = (unsigned)__shfl_xor((int)x0, 32);
        const unsigned y1 = (unsigned)__shfl_xor((int)x1, 32);
        uint4 pu;
        pu.x = hl ? y0 : lo0;
        pu.y = hl ? y1 : lo1;
        pu.z = hl ? hi0 : y0;
        pu.w = hl ? hi1 : y1;
        const f16x8 pa = __builtin_bit_cast(f16x8, pu);
        oacc = __builtin_amdgcn_mfma_f32_32x32x16_f16(pa, vb, oacc, 0, 0, 0);
    }

    // ---- store this half: O[i][d], d = l31 ----
    float* obase = out + (size_t)b * NTOK * (NH * HD) + h * HD + l31;
    #pragma unroll
    for (int r = 0; r < 16; ++r) {
        const int io = (r & 3) + 8 * (r >> 2) + 4 * hl + 32 * it;
        if (io < NTOK) obase[(size_t)io * (NH * HD)] = oacc[r];
    }
}

extern "C" void kernel_launch(void* const* d_in, const int* in_sizes, int n_in,
                              void* d_out, int out_size, void* d_ws, size_t ws_size,
                              hipStream_t stream) {
    const float* qkv  = (const float*)d_in[0];
    const float* mask = (const float*)d_in[1];
    const float* rot  = (const float*)d_in[2];
    float* out = (float*)d_out;

    const int Btot = in_sizes[0] / (NTOK * CIN);  // 4096
    dim3 grid(Btot);

    const size_t cm_bytes = (size_t)NW * NH * NPAD * NPAD * sizeof(float);  // 4 MiB
    if (ws_size >= cm_bytes && d_ws != nullptr) {
        float* cmT = (float*)d_ws;
        prep_cmask<<<dim3(NW * NH), 64, 0, stream>>>(mask, rot, cmT);
        win_attn_mfma<true><<<grid, 512, 0, stream>>>(qkv, mask, rot, cmT, out);
    } else {
        win_attn_mfma<false><<<grid, 512, 0, stream>>>(qkv, mask, rot, nullptr, out);
    }
}